// Round 3
// baseline (278.178 us; speedup 1.0000x reference)
//
#include <hip/hip_runtime.h>
#include <hip/hip_fp16.h>
#include <math.h>

#define N_NODES 50000
#define N_EDGES 1600000
#define NEG 0.2f

#define PB 256                                // scatter chunks (6250 edges each)
#define CHUNK (N_EDGES / PB)                  // 6250 exactly
#define EPT 25                                // edges per thread (ceil(6250/256))
#define BSHIFT 4
#define NBUCK (N_NODES >> BSHIFT)             // 3125 fine buckets of 16 nodes (exact)
#define STRIDE 768                            // fixed per-bucket region: lambda=512, +11 sigma
#define GEMMB ((N_NODES + 31) / 32)           // 1563 gemm blocks

// h1 stored as 4 channel-group planes of [N_NODES][16 half2] (3.2 MB each, L2-resident per XCD pair).
// as1/ad1 stored as 4 planes of [N_NODES][2 heads] floats (0.4 MB each).
#define H1PLANE 800000                        // half2 units per plane (50000*16)
#define ASPLANE 100000                        // floats per plane (50000*2)

// ---------------- fused: blocks [0,PB) fine-scatter edges; blocks [PB,..) h1 = x @ W1 ----------------

__global__ __launch_bounds__(256) void scatter_gemm(const int* __restrict__ ei, int* __restrict__ bcnt,
                                                    int* __restrict__ temp,
                                                    const float* __restrict__ x, const float* __restrict__ W1,
                                                    const float* __restrict__ att_s, const float* __restrict__ att_d,
                                                    __half2* __restrict__ h1p, float* __restrict__ asp,
                                                    float* __restrict__ adp) {
    __shared__ union {
        float xs[128][36];                     // 18.4 KB (gemm)
        int cur[NBUCK];                        // 12.5 KB (scatter)
    } u;
    int t = threadIdx.x;
    if (blockIdx.x < PB) {
        // ---- fine scatter, edges register-cached across passes ----
        int p = blockIdx.x;
        for (int i = t; i < NBUCK; i += 256) u.cur[i] = 0;
        __syncthreads();
        int e0 = p * CHUNK;
        int vc[EPT];
#pragma unroll
        for (int k = 0; k < EPT; ++k) {
            vc[k] = -1;
            int off = t + k * 256;
            if (off < CHUNK) {
                int e = e0 + off;
                int s = ei[e];
                int d = ei[N_EDGES + e];
                vc[k] = s | (d << 16);         // both < 65536
                atomicAdd(&u.cur[d >> BSHIFT], 1);  // LDS histogram
            }
        }
        __syncthreads();
        for (int i = t; i < NBUCK; i += 256) {
            int h = u.cur[i];
            int c = i * STRIDE;
            if (h) c += atomicAdd(&bcnt[i], h);  // one global atomic per (block,bucket)
            u.cur[i] = c;
        }
        __syncthreads();
#pragma unroll
        for (int k = 0; k < EPT; ++k) {
            int v = vc[k];
            if (v != -1) {
                unsigned d = (unsigned)v >> 16;
                int b = d >> BSHIFT;
                int pos = atomicAdd(&u.cur[b], 1);   // LDS cursor
                if (pos < (b + 1) * STRIDE)          // overflow guard (never fires: +11 sigma)
                    temp[pos] = (v & 0xFFFF) | ((d & 15) << 16);
            }
        }
        return;
    }
    // ---- gemm: 32 rows/block, 4x4 register blocking ----
    int n0 = (blockIdx.x - PB) * 32;
#pragma unroll
    for (int i = 0; i < 16; ++i) {
        int f = i * 256 + t;
        int r = f >> 7, c = f & 127;
        int gr = n0 + r;
        float v = (gr < N_NODES) ? x[(size_t)gr * 128 + c] : 0.f;
        u.xs[c][r] = v;
    }
    __syncthreads();
    int c0 = (t & 31) * 4;
    int r0 = (t >> 5) * 4;
    float acc[4][4];
#pragma unroll
    for (int i = 0; i < 4; ++i)
#pragma unroll
        for (int j = 0; j < 4; ++j) acc[i][j] = 0.f;
#pragma unroll 4
    for (int k = 0; k < 128; ++k) {
        float4 w = *(const float4*)(W1 + k * 128 + c0);
        float4 xr = *(const float4*)(&u.xs[k][r0]);
        float xv[4] = {xr.x, xr.y, xr.z, xr.w};
        float wv[4] = {w.x, w.y, w.z, w.w};
#pragma unroll
        for (int i = 0; i < 4; ++i)
#pragma unroll
            for (int j = 0; j < 4; ++j) acc[i][j] += xv[i] * wv[j];
    }
    int gplane = c0 >> 5;                  // channel group 0..3
    int within = (c0 & 31) >> 1;           // half2 idx inside plane row (0,2,..,14)
#pragma unroll
    for (int i = 0; i < 4; ++i) {
        int row = n0 + r0 + i;
        if (row < N_NODES) {
            __half2 p0 = __float22half2_rn(make_float2(acc[i][0], acc[i][1]));
            __half2 p1 = __float22half2_rn(make_float2(acc[i][2], acc[i][3]));
            size_t hb = (size_t)gplane * H1PLANE + (size_t)row * 16 + within;
            h1p[hb] = p0;
            h1p[hb + 1] = p1;
        }
    }
    int head = (t & 31) >> 2;
    float ps[4], pd[4];
#pragma unroll
    for (int i = 0; i < 4; ++i) {
        float s = 0.f, d = 0.f;
#pragma unroll
        for (int j = 0; j < 4; ++j) {
            s += acc[i][j] * att_s[c0 + j];
            d += acc[i][j] * att_d[c0 + j];
        }
        ps[i] = s; pd[i] = d;
    }
#pragma unroll
    for (int i = 0; i < 4; ++i) {
        ps[i] += __shfl_xor(ps[i], 1, 64);
        ps[i] += __shfl_xor(ps[i], 2, 64);
        pd[i] += __shfl_xor(pd[i], 1, 64);
        pd[i] += __shfl_xor(pd[i], 2, 64);
    }
    if ((t & 3) == 0) {
        int plane = head >> 1, sub = head & 1;
#pragma unroll
        for (int i = 0; i < 4; ++i) {
            int row = n0 + r0 + i;
            if (row < N_NODES) {
                asp[(size_t)plane * ASPLANE + row * 2 + sub] = ps[i];
                adp[(size_t)plane * ASPLANE + row * 2 + sub] = pd[i];
            }
        }
    }
}

// ---------------- CSR sort: one block per bucket, builds node-sorted u16 adjacency + per-node deg/off ----

__global__ __launch_bounds__(128) void sort_kernel(const int* __restrict__ temp, const int* __restrict__ bcnt,
                                                   ushort* __restrict__ sadj, int* __restrict__ ndeg,
                                                   int* __restrict__ noff) {
    __shared__ int lsrc[STRIDE];
    __shared__ int cnt[16];
    __shared__ int cur[16];
    __shared__ int lrp[16];
    int b = blockIdx.x, t = threadIdx.x;
    int base = b * STRIDE;
    int nE = min(bcnt[b], STRIDE);
    if (t < 16) cnt[t] = 0;
    __syncthreads();
    for (int i = t; i < nE; i += 128)
        atomicAdd(&cnt[(unsigned)temp[base + i] >> 16], 1);
    __syncthreads();
    if (t < 16) {
        int v = cnt[t];
        int incl = v;
#pragma unroll
        for (int off = 1; off < 16; off <<= 1) {
            int u = __shfl_up(incl, off, 16);
            if (t >= off) incl += u;
        }
        int excl = incl - v;
        lrp[t] = excl;
        cur[t] = excl;
    }
    __syncthreads();
    for (int i = t; i < nE; i += 128) {
        int v = temp[base + i];
        int pos = atomicAdd(&cur[(unsigned)v >> 16], 1);
        lsrc[pos] = v & 0xFFFF;
    }
    __syncthreads();
    for (int i = t; i < nE; i += 128)
        sadj[base + i] = (ushort)lsrc[i];
    if (t < 16) {
        ndeg[b * 16 + t] = cnt[t];
        noff[b * 16 + t] = base + lrp[t];
    }
}

// ---------------- layer-1 aggregation: channel-group split, CSR, no LDS ----------------
// Block = 256 thr (4 waves), 16 nodes, channel group g = blockIdx&3 (2 heads x 16 ch).
// Under blockIdx%8 XCD round-robin, group g lives only on XCDs {g, g+4}: its 3.2 MB h1
// plane + 0.4 MB as plane are L2-resident -> the 410 MB edge gather is served by L2.
// 16 lanes/edge, 4 edges/chunk, unroll x2 -> 6 independent loads in flight, 1 exp instr
// per 4 edges. Partial 32-ch dot with W2 combined across groups via atomicAdd into h2.

__device__ __forceinline__ float lrelu(float v) { return fmaxf(v, NEG * v); }

__global__ __launch_bounds__(256) void agg1_kernel(const __half2* __restrict__ h1p, const float* __restrict__ asp,
                                                   const float* __restrict__ adp, const ushort* __restrict__ sadj,
                                                   const int* __restrict__ ndeg, const int* __restrict__ noff,
                                                   const float* __restrict__ b1, const float* __restrict__ W2,
                                                   float* __restrict__ h2out) {
    int g = blockIdx.x & 3;
    int nb = (blockIdx.x >> 2) * 16;
    int t = threadIdx.x;
    int lane = t & 63;
    int wave = t >> 6;                  // 0..3, 4 nodes each
    int hs = (lane >> 3) & 1;           // head within group
    int cl = lane & 15;                 // half2 (channel-pair) index within 32-ch slice
    int e = lane >> 4;                  // edge slot 0..3
    bool e0 = (e == 0);
    const float* aspg = asp + (size_t)g * ASPLANE;
    const float* adpg = adp + (size_t)g * ASPLANE;
    const __half2* h1g = h1p + (size_t)g * H1PLANE;

    for (int kk = 0; kk < 4; ++kk) {
        int n = nb + wave * 4 + kk;     // < 50000 always

        float adP = adpg[n * 2 + hs];
        float asC = aspg[n * 2 + hs];
        float ps = __expf(lrelu(asC + adP));
        __half2 hvs = h1g[n * 16 + cl];
        float acc0 = e0 ? ps * __half2float(__low2half(hvs)) : 0.f;
        float acc1 = e0 ? ps * __half2float(__high2half(hvs)) : 0.f;
        float l = e0 ? ps : 0.f;

        int jb = noff[n];
        int deg = ndeg[n];
        int j = 0;
        for (; j + 8 <= deg; j += 8) {  // two fully-active 4-edge sub-chunks
            int sA = sadj[jb + j + e];
            int sB = sadj[jb + j + 4 + e];
            float aA = aspg[sA * 2 + hs];
            float aB = aspg[sB * 2 + hs];
            __half2 hA = h1g[sA * 16 + cl];
            __half2 hB = h1g[sB * 16 + cl];
            float pA = __expf(lrelu(aA + adP));
            float pB = __expf(lrelu(aB + adP));
            acc0 += pA * __half2float(__low2half(hA));
            acc1 += pA * __half2float(__high2half(hA));
            l += pA;
            acc0 += pB * __half2float(__low2half(hB));
            acc1 += pB * __half2float(__high2half(hB));
            l += pB;
        }
        for (; j < deg; j += 4) {       // masked tail
            int idx = j + e;
            bool act = idx < deg;
            int s = act ? (int)sadj[jb + idx] : n;
            float a = aspg[s * 2 + hs];
            __half2 hv = h1g[s * 16 + cl];
            float p = act ? __expf(lrelu(a + adP)) : 0.f;
            acc0 += p * __half2float(__low2half(hv));
            acc1 += p * __half2float(__high2half(hv));
            l += p;
        }

        // reduce over the 4 edge slots (lane bits 4,5)
        acc0 += __shfl_xor(acc0, 16, 64);
        acc0 += __shfl_xor(acc0, 32, 64);
        acc1 += __shfl_xor(acc1, 16, 64);
        acc1 += __shfl_xor(acc1, 32, 64);
        l += __shfl_xor(l, 16, 64);
        l += __shfl_xor(l, 32, 64);

        float inv = 1.f / (l + 1e-16f);
        int c = g * 32 + cl * 2;
        float y0 = acc0 * inv + b1[c];
        float y1 = acc1 * inv + b1[c + 1];
        y0 = y0 > 0.f ? y0 : expm1f(y0);
        y1 = y1 > 0.f ? y1 : expm1f(y1);
        float part = e0 ? (y0 * W2[c] + y1 * W2[c + 1]) : 0.f;
#pragma unroll
        for (int off = 32; off; off >>= 1) part += __shfl_down(part, off, 64);
        if (lane == 0) atomicAdd(&h2out[n], part);
    }
}

// ---------------- layer-2 aggregation: CSR, no LDS, 8 lanes per node ----------------

__global__ __launch_bounds__(128) void agg2_kernel(const float* __restrict__ h2, const ushort* __restrict__ sadj,
                                                   const int* __restrict__ ndeg, const int* __restrict__ noff,
                                                   const float* __restrict__ att_s2, const float* __restrict__ att_d2,
                                                   const float* __restrict__ b2, float* __restrict__ out) {
    int b = blockIdx.x, t = threadIdx.x;
    float asw = att_s2[0], adw = att_d2[0];
    int sub = t & 7;
    int n = b * 16 + (t >> 3);          // 3125*16 = 50000 exact
    float h2n = h2[n];
    float ad = h2n * adw;
    float acc = 0.f, l = 0.f;
    if (sub == 0) {
        float p = __expf(lrelu(h2n * asw + ad));
        acc = p * h2n;
        l = p;
    }
    int jb = noff[n];
    int deg = ndeg[n];
    for (int jj = sub; jj < deg; jj += 8) {
        int s = sadj[jb + jj];
        float hsv = h2[s];
        float p = __expf(lrelu(hsv * asw + ad));
        acc += p * hsv;
        l += p;
    }
#pragma unroll
    for (int off = 4; off; off >>= 1) {
        acc += __shfl_down(acc, off, 8);
        l += __shfl_down(l, off, 8);
    }
    if (sub == 0) out[n] = acc / (l + 1e-16f) + b2[0];
}

// ---------------- launch ----------------

extern "C" void kernel_launch(void* const* d_in, const int* in_sizes, int n_in,
                              void* d_out, int out_size, void* d_ws, size_t ws_size,
                              hipStream_t stream) {
    const float* x = (const float*)d_in[0];
    const int* ei = (const int*)d_in[1];
    const float* W1 = (const float*)d_in[2];
    const float* att_s1 = (const float*)d_in[3];
    const float* att_d1 = (const float*)d_in[4];
    const float* b1 = (const float*)d_in[5];
    const float* W2 = (const float*)d_in[6];
    const float* att_s2 = (const float*)d_in[7];
    const float* att_d2 = (const float*)d_in[8];
    const float* b2 = (const float*)d_in[9];
    float* out = (float*)d_out;

    char* p = (char*)d_ws;
    auto alloc = [&](size_t bytes) {
        char* q = p;
        p += (bytes + 255) & ~(size_t)255;
        return q;
    };
    int* bcnt = (int*)alloc((size_t)NBUCK * 4);
    int* temp = (int*)alloc((size_t)NBUCK * STRIDE * 4);       // 9.6 MB fine regions
    ushort* sadj = (ushort*)alloc((size_t)NBUCK * STRIDE * 2); // 4.8 MB sorted u16 adjacency
    int* ndeg = (int*)alloc((size_t)N_NODES * 4);
    int* noff = (int*)alloc((size_t)N_NODES * 4);
    __half2* h1p = (__half2*)alloc((size_t)4 * H1PLANE * 4);   // 12.8 MB, 4 planes
    float* asp = (float*)alloc((size_t)4 * ASPLANE * 4);       // 1.6 MB, 4 planes
    float* adp = (float*)alloc((size_t)4 * ASPLANE * 4);
    float* h2 = (float*)alloc((size_t)N_NODES * 4);

    hipMemsetAsync(bcnt, 0, (size_t)NBUCK * 4, stream);
    hipMemsetAsync(h2, 0, (size_t)N_NODES * 4, stream);
    scatter_gemm<<<PB + GEMMB, 256, 0, stream>>>(ei, bcnt, temp,
                                                 x, W1, att_s1, att_d1, h1p, asp, adp);
    sort_kernel<<<NBUCK, 128, 0, stream>>>(temp, bcnt, sadj, ndeg, noff);
    agg1_kernel<<<NBUCK * 4, 256, 0, stream>>>(h1p, asp, adp, sadj, ndeg, noff, b1, W2, h2);
    agg2_kernel<<<NBUCK, 128, 0, stream>>>(h2, sadj, ndeg, noff, att_s2, att_d2, b2, out);
}

// Round 4
// 272.822 us; speedup vs baseline: 1.0196x; 1.0196x over previous
//
#include <hip/hip_runtime.h>
#include <hip/hip_fp16.h>
#include <math.h>

#define N_NODES 50000
#define N_EDGES 1600000
#define NEG 0.2f
#define LOG2E 1.44269504f

#define PB 256                                // scatter chunks (6250 edges each)
#define CHUNK (N_EDGES / PB)                  // 6250 exactly
#define EPT 25                                // edges per thread (ceil(6250/256))
#define BSHIFT 4
#define NBUCK (N_NODES >> BSHIFT)             // 3125 fine buckets of 16 nodes (exact)
#define STRIDE 768                            // per-bucket region: lambda=512+16 self+~56 pad, +7 sigma
#define GEMMB ((N_NODES + 31) / 32)           // 1563 gemm blocks

// h1 stored as 4 channel-group planes of [N_NODES][16 half2] (3.2 MB each, L2-resident per XCD pair).
// as1/ad1 stored as 4 planes of [N_NODES][2 heads] floats, PRE-SCALED by log2e; as planes have a
// sentinel entry at node 50000 (= -3e38) so padded CSR entries yield p = 0.
#define H1PLANE 800000                        // half2 units per plane (50000*16)
#define ASPLANE 100004                        // floats per plane (50000*2 + sentinel pad)

// ---------------- fused: blocks [0,PB) fine-scatter edges; blocks [PB,..) h1 = x @ W1 ----------------

__global__ __launch_bounds__(256) void scatter_gemm(const int* __restrict__ ei, int* __restrict__ bcnt,
                                                    int* __restrict__ temp,
                                                    const float* __restrict__ x, const float* __restrict__ W1,
                                                    const float* __restrict__ att_s, const float* __restrict__ att_d,
                                                    __half2* __restrict__ h1p, float* __restrict__ asp,
                                                    float* __restrict__ adp) {
    __shared__ union {
        float xs[128][36];                     // 18.4 KB (gemm)
        int cur[NBUCK];                        // 12.5 KB (scatter)
    } u;
    int t = threadIdx.x;
    if (blockIdx.x < PB) {
        // ---- fine scatter, edges register-cached across passes ----
        int p = blockIdx.x;
        for (int i = t; i < NBUCK; i += 256) u.cur[i] = 0;
        __syncthreads();
        int e0 = p * CHUNK;
        int vc[EPT];
#pragma unroll
        for (int k = 0; k < EPT; ++k) {
            vc[k] = -1;
            int off = t + k * 256;
            if (off < CHUNK) {
                int e = e0 + off;
                int s = ei[e];
                int d = ei[N_EDGES + e];
                vc[k] = s | (d << 16);         // both < 65536
                atomicAdd(&u.cur[d >> BSHIFT], 1);  // LDS histogram
            }
        }
        __syncthreads();
        for (int i = t; i < NBUCK; i += 256) {
            int h = u.cur[i];
            int c = i * STRIDE;
            if (h) c += atomicAdd(&bcnt[i], h);  // one global atomic per (block,bucket)
            u.cur[i] = c;
        }
        __syncthreads();
#pragma unroll
        for (int k = 0; k < EPT; ++k) {
            int v = vc[k];
            if (v != -1) {
                unsigned d = (unsigned)v >> 16;
                int b = d >> BSHIFT;
                int pos = atomicAdd(&u.cur[b], 1);   // LDS cursor
                if (pos < (b + 1) * STRIDE)          // overflow guard (never fires)
                    temp[pos] = (v & 0xFFFF) | ((d & 15) << 16);
            }
        }
        return;
    }
    // ---- gemm: 32 rows/block, 4x4 register blocking ----
    int n0 = (blockIdx.x - PB) * 32;
#pragma unroll
    for (int i = 0; i < 16; ++i) {
        int f = i * 256 + t;
        int r = f >> 7, c = f & 127;
        int gr = n0 + r;
        float v = (gr < N_NODES) ? x[(size_t)gr * 128 + c] : 0.f;
        u.xs[c][r] = v;
    }
    __syncthreads();
    int c0 = (t & 31) * 4;
    int r0 = (t >> 5) * 4;
    float acc[4][4];
#pragma unroll
    for (int i = 0; i < 4; ++i)
#pragma unroll
        for (int j = 0; j < 4; ++j) acc[i][j] = 0.f;
#pragma unroll 4
    for (int k = 0; k < 128; ++k) {
        float4 w = *(const float4*)(W1 + k * 128 + c0);
        float4 xr = *(const float4*)(&u.xs[k][r0]);
        float xv[4] = {xr.x, xr.y, xr.z, xr.w};
        float wv[4] = {w.x, w.y, w.z, w.w};
#pragma unroll
        for (int i = 0; i < 4; ++i)
#pragma unroll
            for (int j = 0; j < 4; ++j) acc[i][j] += xv[i] * wv[j];
    }
    int gplane = c0 >> 5;                  // channel group 0..3
    int within = (c0 & 31) >> 1;           // half2 idx inside plane row
#pragma unroll
    for (int i = 0; i < 4; ++i) {
        int row = n0 + r0 + i;
        if (row < N_NODES) {
            __half2 p0 = __float22half2_rn(make_float2(acc[i][0], acc[i][1]));
            __half2 p1 = __float22half2_rn(make_float2(acc[i][2], acc[i][3]));
            size_t hb = (size_t)gplane * H1PLANE + (size_t)row * 16 + within;
            h1p[hb] = p0;
            h1p[hb + 1] = p1;
        }
    }
    int head = (t & 31) >> 2;
    float ps[4], pd[4];
#pragma unroll
    for (int i = 0; i < 4; ++i) {
        float s = 0.f, d = 0.f;
#pragma unroll
        for (int j = 0; j < 4; ++j) {
            s += acc[i][j] * att_s[c0 + j];
            d += acc[i][j] * att_d[c0 + j];
        }
        ps[i] = s; pd[i] = d;
    }
#pragma unroll
    for (int i = 0; i < 4; ++i) {
        ps[i] += __shfl_xor(ps[i], 1, 64);
        ps[i] += __shfl_xor(ps[i], 2, 64);
        pd[i] += __shfl_xor(pd[i], 1, 64);
        pd[i] += __shfl_xor(pd[i], 2, 64);
    }
    if ((t & 3) == 0) {
        int plane = head >> 1, sub = head & 1;
#pragma unroll
        for (int i = 0; i < 4; ++i) {
            int row = n0 + r0 + i;
            if (row < N_NODES) {
                asp[(size_t)plane * ASPLANE + row * 2 + sub] = ps[i] * LOG2E;  // pre-scaled: p = exp2(lrelu(a'+d'))
                adp[(size_t)plane * ASPLANE + row * 2 + sub] = pd[i] * LOG2E;
            }
        }
    }
}

// ---------------- CSR sort: self-loop prepended, list padded to multiple of 8 with phantom node 50000 ----

__global__ __launch_bounds__(128) void sort_kernel(const int* __restrict__ temp, const int* __restrict__ bcnt,
                                                   ushort* __restrict__ sadj, int* __restrict__ ndeg,
                                                   int* __restrict__ noff, float* __restrict__ asp) {
    __shared__ int cnt[16];
    __shared__ int cur[16];
    int b = blockIdx.x, t = threadIdx.x;
    int base = b * STRIDE;
    int nE = min(bcnt[b], STRIDE);
    if (t < 16) cnt[t] = 0;
    __syncthreads();
    for (int i = t; i < nE; i += 128)
        atomicAdd(&cnt[(unsigned)temp[base + i] >> 16], 1);
    __syncthreads();
    if (t < 16) {
        int dr = cnt[t] + 1;                 // + self-loop
        int p8 = (dr + 7) & ~7;              // padded length
        int incl = p8;
#pragma unroll
        for (int off = 1; off < 16; off <<= 1) {
            int u = __shfl_up(incl, off, 16);
            if (t >= off) incl += u;
        }
        int excl = incl - p8;
        cur[t] = excl + 1;                   // slot 0 reserved for self
        int node = b * 16 + t;
        if (excl < STRIDE) sadj[base + excl] = (ushort)node;        // self first
        for (int z = excl + dr; z < excl + p8 && z < STRIDE; ++z)   // phantom padding (p = 0)
            sadj[base + z] = (ushort)N_NODES;
        ndeg[node] = dr;                     // raw (self incl., no padding) — agg2 bound
        noff[node] = base + excl;
    }
    __syncthreads();
    for (int i = t; i < nE; i += 128) {
        int v = temp[base + i];
        int pos = atomicAdd(&cur[(unsigned)v >> 16], 1);
        if (pos < STRIDE) sadj[base + pos] = (ushort)(v & 0xFFFF);
    }
    if (b == 0 && t < 8)                     // as-plane sentinels: phantom node -> p = 0
        asp[(size_t)(t >> 1) * ASPLANE + 2 * N_NODES + (t & 1)] = -3.0e38f;
}

// ---------------- layer-1 aggregation: 4-group channel split, CSR, dwordx2 gathers, no LDS ----------------
// Block = 256 thr (4 waves), 16 nodes, group g = blockIdx&3 (2 heads x 16 ch); g -> XCDs {g, g+4}
// keeps the 3.2 MB h1 plane + as plane L2-resident (R3: FETCH 202->33 MB, HW-confirmed).
// Wave = 8 edge-slots x 8 lanes; each lane carries 4 channels (dwordx2 = 2 half2): one iteration
// covers 8 edges in ~19 instr (R3: 31 instr/8 edges). Padded CSR -> no tail, no masks, no self
// preamble. p = exp2(max(v, 0.2v)) on pre-scaled attention values.

__device__ __forceinline__ float lrelu(float v) { return fmaxf(v, NEG * v); }

__global__ __launch_bounds__(256) void agg1_kernel(const __half2* __restrict__ h1p, const float* __restrict__ asp,
                                                   const float* __restrict__ adp, const ushort* __restrict__ sadj,
                                                   const int* __restrict__ ndeg, const int* __restrict__ noff,
                                                   const float* __restrict__ b1, const float* __restrict__ W2,
                                                   float* __restrict__ h2out) {
    int g = blockIdx.x & 3;
    int nb = (blockIdx.x >> 2) * 16;
    int t = threadIdx.x;
    int lane = t & 63;
    int wave = t >> 6;                  // 0..3, 4 nodes each
    int e = lane >> 3;                  // edge slot 0..7
    int q = lane & 7;                   // channel quad (ch 4q..4q+3 of this 32-ch group)
    int hs = q >> 2;                    // head within group owning these channels
    const float* aspg = asp + (size_t)g * ASPLANE;
    const float* adpg = adp + (size_t)g * ASPLANE;
    const float2* h1g = (const float2*)(h1p + (size_t)g * H1PLANE);  // 8 float2 (4B-half2 pairs) per row

    for (int kk = 0; kk < 4; ++kk) {
        int n = nb + wave * 4 + kk;     // < 50000 always

        float adP = adpg[n * 2 + hs];
        int jb = noff[n];
        int dr = ndeg[n];
        int dp = (dr + 7) & ~7;         // padded bound (list is phantom-padded to this)
        float a0 = 0.f, a1 = 0.f, a2 = 0.f, a3 = 0.f, l = 0.f;

        for (int j = e; j < dp; j += 8) {
            int s = sadj[jb + j];
            float av = aspg[s * 2 + hs];            // phantom -> -3e38 -> p = 0
            int sh = min(s, N_NODES - 1);           // clamp phantom for h1 read
            float2 hv = h1g[sh * 8 + q];
            __half2 h01 = *(const __half2*)&hv.x;
            __half2 h23 = *(const __half2*)&hv.y;
            float v = av + adP;
            float p = exp2f(fmaxf(v, NEG * v));
            a0 += p * __half2float(__low2half(h01));    // v_fma_mix
            a1 += p * __half2float(__high2half(h01));
            a2 += p * __half2float(__low2half(h23));
            a3 += p * __half2float(__high2half(h23));
            l += p;
        }

        // reduce over the 8 edge slots (lane bits 3,4,5)
#pragma unroll
        for (int off = 8; off <= 32; off <<= 1) {
            a0 += __shfl_xor(a0, off, 64);
            a1 += __shfl_xor(a1, off, 64);
            a2 += __shfl_xor(a2, off, 64);
            a3 += __shfl_xor(a3, off, 64);
            l  += __shfl_xor(l,  off, 64);
        }

        float inv = 1.f / (l + 1e-16f);
        int c = g * 32 + q * 4;
        float y0 = a0 * inv + b1[c];
        float y1 = a1 * inv + b1[c + 1];
        float y2 = a2 * inv + b1[c + 2];
        float y3 = a3 * inv + b1[c + 3];
        y0 = y0 > 0.f ? y0 : expm1f(y0);
        y1 = y1 > 0.f ? y1 : expm1f(y1);
        y2 = y2 > 0.f ? y2 : expm1f(y2);
        y3 = y3 > 0.f ? y3 : expm1f(y3);
        float part = y0 * W2[c] + y1 * W2[c + 1] + y2 * W2[c + 2] + y3 * W2[c + 3];
        part += __shfl_xor(part, 1, 64);
        part += __shfl_xor(part, 2, 64);
        part += __shfl_xor(part, 4, 64);
        if (lane == 0) atomicAdd(&h2out[n], part);
    }
}

// ---------------- layer-2 aggregation: CSR (self in list, raw-deg bound skips padding), 8 lanes/node ----

__global__ __launch_bounds__(128) void agg2_kernel(const float* __restrict__ h2, const ushort* __restrict__ sadj,
                                                   const int* __restrict__ ndeg, const int* __restrict__ noff,
                                                   const float* __restrict__ att_s2, const float* __restrict__ att_d2,
                                                   const float* __restrict__ b2, float* __restrict__ out) {
    int b = blockIdx.x, t = threadIdx.x;
    float asw = att_s2[0], adw = att_d2[0];
    int sub = t & 7;
    int n = b * 16 + (t >> 3);          // 3125*16 = 50000 exact
    float ad = h2[n] * adw;
    float acc = 0.f, l = 0.f;
    int jb = noff[n];
    int dr = ndeg[n];                   // raw: self + real edges, no padding
    for (int jj = sub; jj < dr; jj += 8) {
        int s = sadj[jb + jj];
        float hsv = h2[s];
        float p = __expf(lrelu(hsv * asw + ad));
        acc += p * hsv;
        l += p;
    }
#pragma unroll
    for (int off = 4; off; off >>= 1) {
        acc += __shfl_down(acc, off, 8);
        l += __shfl_down(l, off, 8);
    }
    if (sub == 0) out[n] = acc / (l + 1e-16f) + b2[0];
}

// ---------------- launch ----------------

extern "C" void kernel_launch(void* const* d_in, const int* in_sizes, int n_in,
                              void* d_out, int out_size, void* d_ws, size_t ws_size,
                              hipStream_t stream) {
    const float* x = (const float*)d_in[0];
    const int* ei = (const int*)d_in[1];
    const float* W1 = (const float*)d_in[2];
    const float* att_s1 = (const float*)d_in[3];
    const float* att_d1 = (const float*)d_in[4];
    const float* b1 = (const float*)d_in[5];
    const float* W2 = (const float*)d_in[6];
    const float* att_s2 = (const float*)d_in[7];
    const float* att_d2 = (const float*)d_in[8];
    const float* b2 = (const float*)d_in[9];
    float* out = (float*)d_out;

    char* p = (char*)d_ws;
    auto alloc = [&](size_t bytes) {
        char* q = p;
        p += (bytes + 255) & ~(size_t)255;
        return q;
    };
    int* bcnt = (int*)alloc((size_t)NBUCK * 4);
    int* temp = (int*)alloc((size_t)NBUCK * STRIDE * 4);       // 9.6 MB fine regions
    ushort* sadj = (ushort*)alloc((size_t)NBUCK * STRIDE * 2); // 4.8 MB padded u16 CSR
    int* ndeg = (int*)alloc((size_t)N_NODES * 4);
    int* noff = (int*)alloc((size_t)N_NODES * 4);
    __half2* h1p = (__half2*)alloc((size_t)4 * H1PLANE * 4);   // 12.8 MB, 4 planes
    float* asp = (float*)alloc((size_t)4 * ASPLANE * 4);       // pre-scaled, + sentinels
    float* adp = (float*)alloc((size_t)4 * ASPLANE * 4);
    float* h2 = (float*)alloc((size_t)N_NODES * 4);

    hipMemsetAsync(bcnt, 0, (size_t)NBUCK * 4, stream);
    hipMemsetAsync(h2, 0, (size_t)N_NODES * 4, stream);
    scatter_gemm<<<PB + GEMMB, 256, 0, stream>>>(ei, bcnt, temp,
                                                 x, W1, att_s1, att_d1, h1p, asp, adp);
    sort_kernel<<<NBUCK, 128, 0, stream>>>(temp, bcnt, sadj, ndeg, noff, asp);
    agg1_kernel<<<NBUCK * 4, 256, 0, stream>>>(h1p, asp, adp, sadj, ndeg, noff, b1, W2, h2);
    agg2_kernel<<<NBUCK, 128, 0, stream>>>(h2, sadj, ndeg, noff, att_s2, att_d2, b2, out);
}